// Round 16
// baseline (403.510 us; speedup 1.0000x reference)
//
#include <hip/hip_runtime.h>
#include <hip/hip_bf16.h>

// Problem constants
#define BB   64
#define CIN  3
#define HH   224
#define WW   224
#define C1   32
#define H1   112
#define W1   112
#define C2   64
#define H2   56
#define W2   56
#define FEATN 64
#define OUTN 1024
#define K3TOT (FEATN*FEATN*FEATN)   // 262144

typedef __bf16 bf16x8 __attribute__((ext_vector_type(8)));
typedef float  f32x4  __attribute__((ext_vector_type(4)));
typedef unsigned int u32;

__device__ __forceinline__ void gload_lds16(const void* g, void* l) {
  __builtin_amdgcn_global_load_lds((const __attribute__((address_space(1))) u32*)g,
                                   (__attribute__((address_space(3))) u32*)l, 16, 0, 0);
}
// non-temporal variant for single-use streams (w3)
__device__ __forceinline__ void gload_lds16_nt(const void* g, void* l) {
  __builtin_amdgcn_global_load_lds((const __attribute__((address_space(1))) u32*)g,
                                   (__attribute__((address_space(3))) u32*)l, 16, 0, 2);
}

// ---------------- conv1 (+ merged prep): cnt-zero, halo, w2frag, conv ---------
__global__ __launch_bounds__(256) void conv1_kernel(const float* __restrict__ x,
        const float* __restrict__ w1, const float* __restrict__ b1,
        __bf16* __restrict__ h1T, const float* __restrict__ w2,
        __bf16* __restrict__ wf, unsigned* __restrict__ cnt) {
    int gid = blockIdx.x * 256 + threadIdx.x;
    if (gid == 0) *cnt = 0u;                         // re-zero every launch

    // ---- prep section: halo-zero + w2frag
    if (gid < 64 * 452) {
      int b = gid / 452, s = gid - b * 452;
      int row, col;
      if      (s < 114) { row = 0;        col = s; }
      else if (s < 228) { row = 113;      col = s - 114; }
      else if (s < 340) { row = s - 227;  col = 0; }
      else              { row = s - 339;  col = 113; }
      __bf16* p = h1T + (((size_t)b * 114 + row) * 114 + col) * 32;
      bf16x8 z = {};
      #pragma unroll
      for (int k = 0; k < 4; ++k) *(bf16x8*)(p + k * 8) = z;
    } else if (gid < 64 * 452 + 18432) {
      int t = gid - 64 * 452;
      int e    = t & 7;
      int lane = (t >> 3) & 63;
      int q    = (t >> 9) % 9;
      int j    = t / 4608;
      int oc = j * 16 + (lane & 15);
      int c  = (lane >> 4) * 8 + e;
      wf[t] = (__bf16)w2[(oc * C1 + c) * 9 + q];
    }

    // ---- conv section: 2 outputs/thread, float4 row loads
    int pos = gid;                                   // 64*112*56 = 401408
    int b   = pos / (H1 * 56);
    int rem = pos - b * (H1 * 56);
    int oy  = rem / 56;
    int g   = rem - oy * 56;                         // x-pair group: ox = 2g+u
    int iy0 = oy * 2 - 1;

    float win[CIN][3][5];
    #pragma unroll
    for (int c = 0; c < CIN; ++c)
      #pragma unroll
      for (int dy = 0; dy < 3; ++dy) {
        int iy = iy0 + dy;
        bool rv = (iy >= 0) & (iy < HH);
        const float* row = x + ((size_t)(b * CIN + c) * HH + (rv ? iy : 0)) * WW;
        float lf = (rv && g > 0) ? row[4 * g - 1] : 0.f;
        float4 f4 = rv ? *(const float4*)(row + 4 * g) : (float4){0.f, 0.f, 0.f, 0.f};
        win[c][dy][0] = lf;
        win[c][dy][1] = f4.x; win[c][dy][2] = f4.y;
        win[c][dy][3] = f4.z; win[c][dy][4] = f4.w;
      }

    float acc[2][C1];
    #pragma unroll
    for (int u = 0; u < 2; ++u)
      #pragma unroll
      for (int oc = 0; oc < C1; ++oc) acc[u][oc] = b1[oc];

    #pragma unroll
    for (int c = 0; c < CIN; ++c)
      #pragma unroll
      for (int dy = 0; dy < 3; ++dy)
        #pragma unroll
        for (int dx = 0; dx < 3; ++dx) {
          float w0 = win[c][dy][dx];
          float w1v = win[c][dy][dx + 2];
          const float* wq = w1 + c * 9 + dy * 3 + dx;
          #pragma unroll
          for (int oc = 0; oc < C1; ++oc) {
            float wv = wq[oc * 27];
            acc[0][oc] = fmaf(wv, w0, acc[0][oc]);
            acc[1][oc] = fmaf(wv, w1v, acc[1][oc]);
          }
        }

    __bf16* dst = h1T + (((size_t)b * 114 + oy + 1) * 114 + (2 * g) + 1) * 32;
    #pragma unroll
    for (int u = 0; u < 2; ++u) {
      bf16x8 outv[4];
      #pragma unroll
      for (int k = 0; k < 32; ++k)
        outv[k >> 3][k & 7] = (__bf16)fmaxf(acc[u][k], 0.f);
      #pragma unroll
      for (int k = 0; k < 4; ++k) *(bf16x8*)(dst + u * 32 + k * 8) = outv[k];
    }
}

// --- conv2 + fused pool + fused center (last-block-done) ----------------------
#define CONV2_GRID 1792
__global__ __launch_bounds__(256) void conv2_kernel(const __bf16* __restrict__ h1T,
        const __bf16* __restrict__ wf, const float* __restrict__ b2,
        float* __restrict__ featp, float* __restrict__ fcv,
        float* __restrict__ fmean, unsigned* __restrict__ cnt) {
    __shared__ __align__(16) char tile[2304 * 16];   // 36864 B
    __shared__ float pool_red[4][64];
    __shared__ unsigned lastf;
    int t = threadIdx.x;
    int bid = blockIdx.x;                            // 64*28 = 1792
    int b  = bid / 28;
    int yt = bid - b * 28;
    int y0 = yt * 2;
    int w = t >> 6, lane = t & 63, l15 = lane & 15, l4 = lane >> 4;

    const char* src_base = (const char*)(h1T + ((size_t)b * 114 + 2 * y0) * 114 * 32);
    #pragma unroll
    for (int i = 0; i < 9; ++i) {
      int g = (w * 9 + i) * 64 + lane;
      int site = g >> 2; site = site < 569 ? site : 569;
      int qp = g & 3;
      int r5 = site / 114;
      int col = site - r5 * 114;
      int ql = (qp - col) & 3;
      gload_lds16(src_base + (size_t)site * 64 + ql * 16, tile + (size_t)g * 16);
    }
    __syncthreads();

    int sbase[2], urot[2];
    #pragma unroll
    for (int p = 0; p < 2; ++p) {
      int mt = 2 * w + p;
      int yl = mt >> 2;
      int xl = ((mt & 3) << 4) + l15;
      int xe = xl < 55 ? xl : 55;
      sbase[p] = ((yl * 2) * 114 + 2 * xe) * 64;
      urot[p]  = (l4 + 2 * xe) & 3;
    }

    f32x4 acc[2][4];
    #pragma unroll
    for (int p = 0; p < 2; ++p)
      #pragma unroll
      for (int j = 0; j < 4; ++j) acc[p][j] = (f32x4){0.f, 0.f, 0.f, 0.f};

    #pragma unroll
    for (int q = 0; q < 9; ++q) {
      int dy = q / 3, dx = q % 3;
      bf16x8 bw[4];
      #pragma unroll
      for (int j = 0; j < 4; ++j)
        bw[j] = *(const bf16x8*)(wf + ((j * 9 + q) * 64 + lane) * 8);
      bf16x8 af[2];
      #pragma unroll
      for (int p = 0; p < 2; ++p) {
        int addr = sbase[p] + (dy * 114 + dx) * 64 + (((urot[p] + dx) & 3) << 4);
        af[p] = *(const bf16x8*)(tile + addr);
      }
      #pragma unroll
      for (int p = 0; p < 2; ++p)
        #pragma unroll
        for (int j = 0; j < 4; ++j)
          acc[p][j] = __builtin_amdgcn_mfma_f32_16x16x32_bf16(af[p], bw[j], acc[p][j], 0, 0, 0);
    }

    float bias[4];
    #pragma unroll
    for (int j = 0; j < 4; ++j) bias[j] = b2[j * 16 + l15];
    float ps[4] = {0.f, 0.f, 0.f, 0.f};
    #pragma unroll
    for (int p = 0; p < 2; ++p) {
      int mt = 2 * w + p;
      bool valid = ((mt & 3) != 3) || (l4 < 2);      // x<56 mask
      #pragma unroll
      for (int j = 0; j < 4; ++j) {
        float sj = 0.f;
        #pragma unroll
        for (int r = 0; r < 4; ++r)
          sj += fmaxf(acc[p][j][r] + bias[j], 0.f);
        ps[j] += valid ? sj : 0.f;
      }
    }
    #pragma unroll
    for (int j = 0; j < 4; ++j) {
      ps[j] += __shfl_xor(ps[j], 16);
      ps[j] += __shfl_xor(ps[j], 32);
    }
    if (l4 == 0) {
      #pragma unroll
      for (int j = 0; j < 4; ++j) pool_red[w][j * 16 + l15] = ps[j];
    }
    __syncthreads();
    if (t < 64) {
      float s = pool_red[0][t] + pool_red[1][t] + pool_red[2][t] + pool_red[3][t];
      featp[((size_t)yt * 64 + b) * 64 + t] = s;
    }

    // ---- last-block-done fused center: featp -> fcv, fmean -------------------
    __threadfence();                                 // featp visible device-wide
    if (t == 0) {
      unsigned v = __hip_atomic_fetch_add(cnt, 1u, __ATOMIC_ACQ_REL,
                                          __HIP_MEMORY_SCOPE_AGENT);
      lastf = (v == CONV2_GRID - 1) ? 1u : 0u;
    }
    __syncthreads();
    if (lastf) {
      int bb = t >> 2, cq = (t & 3) * 16;            // thread: 16 c's of one b
      float s[16];
      #pragma unroll
      for (int i = 0; i < 16; ++i) s[i] = 0.f;
      #pragma unroll 4
      for (int ytt = 0; ytt < 28; ++ytt) {
        const float* p = featp + ((size_t)ytt * 64 + bb) * 64 + cq;
        #pragma unroll
        for (int q4 = 0; q4 < 4; ++q4) {
          float4 v4 = *(const float4*)(p + q4 * 4);
          s[q4*4+0] += v4.x; s[q4*4+1] += v4.y;
          s[q4*4+2] += v4.z; s[q4*4+3] += v4.w;
        }
      }
      float tot = 0.f;
      #pragma unroll
      for (int i = 0; i < 16; ++i) { s[i] *= (1.f / (H2 * W2)); tot += s[i]; }
      tot += __shfl_xor(tot, 1);
      tot += __shfl_xor(tot, 2);                     // 4-thread group = full b row
      float mean = tot * (1.f / 64.f);
      #pragma unroll
      for (int i = 0; i < 16; ++i) fcv[bb * 64 + cq + i] = s[i] - mean;
      if ((t & 3) == 0) fmean[bb] = mean;
    }
}

// -------- third-order term (R12 row-stream) + FUSED FINALE --------------------
// One block per o; 2 waves x 512 KB halves, 4 KB chunks, dbuf, counted vmcnt.
// Epilogue: this block computes out[b][o] for all 64 b (mean+cov via fcT in
// LDS + identity sum(feat*wm) = sum(fc*wm) + fmean*sum(wm)) + thrd partials.
#define T3_NCH 128          // chunks per wave (512KB / 4KB)

struct T3S {
    float stage[2][2][16][64];   // [wave][buf][ij][k]  32 KB
    float fcT[64][66];           // fcT[c][b], padded   16.9 KB
    float wred[2][64];
    float epi[2][64];
};

__global__ __launch_bounds__(128) void third_kernel(const float* __restrict__ fc,
        const float* __restrict__ w3,
        const float* __restrict__ wm, const float* __restrict__ bm,
        const float* __restrict__ wc, const float* __restrict__ bcv,
        const float* __restrict__ b3, const float* __restrict__ fmean,
        float* __restrict__ out) {
    __shared__ __align__(16) T3S sh;
    int t = threadIdx.x;
    int w = t >> 6, lane = t & 63, l15 = lane & 15, l4 = lane >> 4;
    int o = blockIdx.x;
    int swz = (l15 & 7) << 4;

    // stage fcT[c][b] = fc[b*64+c]
    for (int idx = t; idx < 4096; idx += 128)
      sh.fcT[idx & 63][idx >> 6] = fc[idx];

    const char* seg = (const char*)w3 + ((size_t)o << 20) + (size_t)w * 524288;

    // issue chunk 0 early
    #pragma unroll
    for (int ii = 0; ii < 4; ++ii) {
      int row = ii * 4 + l4;
      int lo  = l15 * 16;
      gload_lds16_nt(seg + row * 256 + (lo ^ ((row & 7) << 4)),
                     (char*)&sh.stage[w][0][0][0] + ii * 1024);
    }

    // B-fragments in registers
    bf16x8 bfrag[2][4];
    #pragma unroll
    for (int ks = 0; ks < 2; ++ks)
      #pragma unroll
      for (int nt = 0; nt < 4; ++nt) {
        const float* p = fc + (nt * 16 + l15) * 64 + ks * 32 + l4 * 8;
        float4 v0 = *(const float4*)p;
        float4 v1 = *(const float4*)(p + 4);
        bfrag[ks][nt][0] = (__bf16)v0.x; bfrag[ks][nt][1] = (__bf16)v0.y;
        bfrag[ks][nt][2] = (__bf16)v0.z; bfrag[ks][nt][3] = (__bf16)v0.w;
        bfrag[ks][nt][4] = (__bf16)v1.x; bfrag[ks][nt][5] = (__bf16)v1.y;
        bfrag[ks][nt][6] = (__bf16)v1.z; bfrag[ks][nt][7] = (__bf16)v1.w;
      }

    __syncthreads();                                 // fcT ready

    float oacc[4] = {0.f, 0.f, 0.f, 0.f};

    #pragma unroll 1
    for (int c = 0; c < T3_NCH; ++c) {
      if (c + 1 < T3_NCH) {
        const char* s2 = seg + (size_t)(c + 1) * 4096;
        char* db = (char*)&sh.stage[w][(c + 1) & 1][0][0];
        #pragma unroll
        for (int ii = 0; ii < 4; ++ii) {
          int row = ii * 4 + l4;
          int lo  = l15 * 16;
          gload_lds16_nt(s2 + row * 256 + (lo ^ ((row & 7) << 4)), db + ii * 1024);
        }
        asm volatile("s_waitcnt vmcnt(4)" ::: "memory");
      } else {
        asm volatile("s_waitcnt vmcnt(0)" ::: "memory");
      }
      __builtin_amdgcn_sched_barrier(0);

      const char* cb = (const char*)&sh.stage[w][c & 1][0][0];
      f32x4 acc[4];
      #pragma unroll
      for (int nt = 0; nt < 4; ++nt) acc[nt] = (f32x4){0.f, 0.f, 0.f, 0.f};
      #pragma unroll
      for (int ks = 0; ks < 2; ++ks) {
        int off0 = l15 * 256 + ((ks * 128 + l4 * 32) ^ swz);
        float4 a0 = *(const float4*)(cb + off0);
        float4 a1 = *(const float4*)(cb + (off0 ^ 16));
        bf16x8 af;
        af[0] = (__bf16)a0.x; af[1] = (__bf16)a0.y;
        af[2] = (__bf16)a0.z; af[3] = (__bf16)a0.w;
        af[4] = (__bf16)a1.x; af[5] = (__bf16)a1.y;
        af[6] = (__bf16)a1.z; af[7] = (__bf16)a1.w;
        #pragma unroll
        for (int nt = 0; nt < 4; ++nt)
          acc[nt] = __builtin_amdgcn_mfma_f32_16x16x32_bf16(af, bfrag[ks][nt], acc[nt], 0, 0, 0);
      }
      int i = w * 32 + (c >> 2);                     // uniform within chunk
      #pragma unroll
      for (int nt = 0; nt < 4; ++nt) {
        int b = nt * 16 + l15;
        float s = 0.f;
        #pragma unroll
        for (int r = 0; r < 4; ++r) {
          int j = (c * 16 + l4 * 4 + r) & 63;
          s = fmaf(sh.fcT[j][b], acc[nt][r], s);
        }
        oacc[nt] = fmaf(sh.fcT[i][b], s, oacc[nt]);
      }
    }

    // reduce thrd partials over l4, then across waves (into LDS)
    #pragma unroll
    for (int nt = 0; nt < 4; ++nt) {
      oacc[nt] += __shfl_xor(oacc[nt], 16);
      oacc[nt] += __shfl_xor(oacc[nt], 32);
    }
    if (l4 == 0) {
      #pragma unroll
      for (int nt = 0; nt < 4; ++nt) sh.wred[w][nt * 16 + l15] = oacc[nt];
    }
    __syncthreads();

    // ---- fused finale: mean + cov for this o, all 64 b -----------------------
    int eb = t & 63;                                 // batch handled by thread
    const float* wcrow = wc + (size_t)o * 4096;
    const float* wmrow = wm + o * 64;
    float fm = fmean[eb];
    float covp = 0.f, meanp = 0.f, wmsump = 0.f;
    #pragma unroll 1
    for (int c1 = w * 32; c1 < w * 32 + 32; ++c1) {
      float a2 = 0.f;
      #pragma unroll
      for (int c2 = 0; c2 < 64; c2 += 4) {
        float4 wv = *(const float4*)(wcrow + c1 * 64 + c2);
        a2 = fmaf(sh.fcT[c2 + 0][eb], wv.x, a2);
        a2 = fmaf(sh.fcT[c2 + 1][eb], wv.y, a2);
        a2 = fmaf(sh.fcT[c2 + 2][eb], wv.z, a2);
        a2 = fmaf(sh.fcT[c2 + 3][eb], wv.w, a2);
      }
      covp = fmaf(sh.fcT[c1][eb], a2, covp);
    }
    #pragma unroll 8
    for (int c = w * 32; c < w * 32 + 32; ++c) {
      float wmv = wmrow[c];
      meanp = fmaf(sh.fcT[c][eb], wmv, meanp);
      wmsump += wmv;
    }
    sh.epi[w][eb] = covp + meanp + fm * wmsump;
    __syncthreads();
    if (t < 64) {
      float res = bm[o] + bcv[o] + b3[o]
                + sh.epi[0][t] + sh.epi[1][t]
                + sh.wred[0][t] + sh.wred[1][t];
      out[t * OUTN + o] = res;
    }
}

extern "C" void kernel_launch(void* const* d_in, const int* in_sizes, int n_in,
                              void* d_out, int out_size, void* d_ws, size_t ws_size,
                              hipStream_t stream) {
    const float* x   = (const float*)d_in[0];
    const float* w1  = (const float*)d_in[1];
    const float* b1  = (const float*)d_in[2];
    const float* w2  = (const float*)d_in[3];
    const float* b2  = (const float*)d_in[4];
    const float* wm  = (const float*)d_in[5];
    const float* bm  = (const float*)d_in[6];
    const float* wc  = (const float*)d_in[7];
    const float* bcv = (const float*)d_in[8];
    const float* w3  = (const float*)d_in[9];
    const float* b3  = (const float*)d_in[10];
    float* out = (float*)d_out;

    // workspace layout (float offsets): h1T (bf16) | featp | fcv | fmean | wfrg | cnt
    float* ws    = (float*)d_ws;
    __bf16* h1T  = (__bf16*)ws;                      // 26,615,808 bf16 = 53.2 MB
    float* featp = ws + 13307904;                    // 28*64*64 = 114,688
    float* fcv   = ws + 13422592;                    // 4096
    float* fmean = ws + 13426688;                    // 64 (padded slot 4096)
    __bf16* wfrg = (__bf16*)(ws + 13430784);         // 18,432 bf16 (9,216 f)
    unsigned* cnt = (unsigned*)(ws + 13440000);      // 1 uint

    conv1_kernel<<<1568, 256, 0, stream>>>(x, w1, b1, h1T, w2, wfrg, cnt);
    conv2_kernel<<<CONV2_GRID, 256, 0, stream>>>(h1T, wfrg, b2, featp, fcv, fmean, cnt);
    third_kernel<<<1024, 128, 0, stream>>>(fcv, w3, wm, bm, wc, bcv, b3, fmean, out);
}